// Round 1
// baseline (11307.898 us; speedup 1.0000x reference)
//
#include <hip/hip_runtime.h>
#include <stdint.h>

#define BATCH 512
#define D_IN  2048
#define D_MCB 16000
#define N_OUT 3000

typedef __bf16 bf16x8 __attribute__((ext_vector_type(8)));
typedef __bf16 bf16x4 __attribute__((ext_vector_type(4)));
typedef float  f32x4  __attribute__((ext_vector_type(4)));

// Native LDS float atomic add (fire-and-forget). addr = 32-bit LDS byte addr.
__device__ __forceinline__ void lds_fadd(unsigned addr, float v) {
    asm volatile("ds_add_f32 %0, %1" :: "v"(addr), "v"(v) : "memory");
}

// ---------------------------------------------------------------------------
// Kernel 1 (R4 rewrite): sparse-pair scatter instead of dense gather.
//   Both count sketches have only 2048 non-zeros, so the circular conv is
//     z[(h1[i]+h2[j]) mod d] += a1[i]*a2[j]   over all 2048x2048 pairs
//   = 4.19M LDS atomic-adds per batch, 8x fewer ops than the 32.8M-FMA
//   gather (R3 kernel: 1594 us, VALUBusy 88%).
//   Per pair: add + wrapped-min + mul + ds_add_f32 (no unpack, no p2 table).
//   LDS: zf[16000] fp32 @ offset 0 (64000 B) + idata[2048] float2 (16384 B)
//   = 80384 B -> 2 blocks/CU, 512 blocks in one wave-round.
//   Wrap trick: byte offsets, pos in [0,128000); wrapped = pos - 64000
//   underflows huge when pos < 64000, so unsigned min = mod. 16000 % 32 == 0
//   so the wrap also preserves LDS bank structure.
// ---------------------------------------------------------------------------
__global__ __launch_bounds__(256, 2) void mcb_pair_kernel(
    const float* __restrict__ x0, const float* __restrict__ x1,
    const float* __restrict__ s1, const float* __restrict__ s2,
    const int* __restrict__ h1, const int* __restrict__ h2,
    __bf16* __restrict__ zb)
{
    __shared__ __align__(16) char smem[80384];
    float*  zf    = (float*)smem;                  // [16000] fp32 accum @ 0
    float2* idata = (float2*)(smem + 64000);       // [2048] (a1, h1 byteoff)

    const int b = blockIdx.x;
    const int t = threadIdx.x;

    // --- phase 1: zero accum; stage per-thread a2/h2 (regs) + shared a1/h1 ---
    for (int k = t; k < D_MCB; k += 256) zf[k] = 0.0f;

    float    a2r[8];
    unsigned h2b[8];
#pragma unroll
    for (int r = 0; r < 8; ++r) {
        int j = t + 256 * r;
        a2r[r] = s2[j] * x1[(size_t)b * D_IN + j];
        h2b[r] = (unsigned)h2[j] << 2;             // byte offset [0, 64000)
    }
    for (int i = t; i < D_IN; i += 256) {
        float a1    = s1[i] * x0[(size_t)b * D_IN + i];
        unsigned p0 = (unsigned)h1[i] << 2;        // byte offset [0, 64000)
        idata[i] = make_float2(a1, __uint_as_float(p0));
    }
    __syncthreads();

    const unsigned zbase = (unsigned)(uintptr_t)zf;

    // --- phase 2: pair scatter. i broadcast (1 ds_read_b64/wave, prefetched),
    //     j per-lane in registers: 8 atomics + ~32 VALU per i per lane. ---
    float2 jd = idata[0];
    for (int i = 0; i < D_IN; ++i) {
        float    a1 = jd.x;
        unsigned p0 = __float_as_uint(jd.y);
        jd = idata[(i + 1) & (D_IN - 1)];          // broadcast prefetch
#pragma unroll
        for (int r = 0; r < 8; ++r) {
            unsigned pos = p0 + h2b[r];            // [0, 128000)
            unsigned wr  = pos - (unsigned)(D_MCB * 4);
            pos = pos < wr ? pos : wr;             // unsigned min == mod 64000
            lds_fadd(zbase + pos, a1 * a2r[r]);
        }
    }
    __syncthreads();

    // --- phase 3: fp32 -> bf16 write-out (coalesced 16 B stores) ---
    for (int c = t; c < D_MCB / 8; c += 256) {
        const float* src = zf + c * 8;
        bf16x8 o;
#pragma unroll
        for (int e = 0; e < 8; ++e) o[e] = (__bf16)src[e];
        *(bf16x8*)(zb + (size_t)b * D_MCB + c * 8) = o;
    }
}

// ---------------------------------------------------------------------------
// Kernel 1.5: W fp32 -> bf16 pre-convert (one pass).
// ---------------------------------------------------------------------------
__global__ __launch_bounds__(256) void wconv_kernel(
    const float* __restrict__ W, __bf16* __restrict__ Wb)
{
    size_t i = ((size_t)blockIdx.x * 256 + threadIdx.x) * 4;
    f32x4 w = *(const f32x4*)(W + i);
    bf16x4 o;
#pragma unroll
    for (int q = 0; q < 4; ++q) o[q] = (__bf16)w[q];
    *(bf16x4*)(Wb + i) = o;
}

// ---------------------------------------------------------------------------
// Kernel 2 (fast path): out = relu(z @ Wb^T + bias), bf16 MFMA 16x16x32.
// ---------------------------------------------------------------------------
__global__ __launch_bounds__(256) void mcb_gemm_bf16_kernel(
    const __bf16* __restrict__ zbm, const __bf16* __restrict__ Wb,
    const float* __restrict__ bias, float* __restrict__ out)
{
    const int lane = threadIdx.x & 63;
    const int wave = threadIdx.x >> 6;
    const int wm = wave >> 1;
    const int wn = wave & 1;
    const int llo = lane & 15;
    const int lhi = lane >> 4;

    const int m0 = blockIdx.y * 64 + wm * 32;
    const int n0 = blockIdx.x * 64 + wn * 32;

    f32x4 acc[2][2] = {};

    const int arow0 = m0 + llo;
    const int bcol0 = n0 + llo;
    const int kk = lhi * 8;

    const __bf16* aptr0 = zbm + (size_t)arow0 * D_MCB + kk;
    const __bf16* aptr1 = aptr0 + (size_t)16 * D_MCB;
    const __bf16* bptr0 = Wb + (size_t)bcol0 * D_MCB + kk;
    const __bf16* bptr1 = bptr0 + (size_t)16 * D_MCB;
    const bool bok0 = (bcol0 < N_OUT);
    const bool bok1 = (bcol0 + 16 < N_OUT);

    for (int k = 0; k < D_MCB; k += 32) {
        bf16x8 a0 = *(const bf16x8*)(aptr0 + k);
        bf16x8 a1 = *(const bf16x8*)(aptr1 + k);
        bf16x8 b0 = {}, b1 = {};
        if (bok0) b0 = *(const bf16x8*)(bptr0 + k);
        if (bok1) b1 = *(const bf16x8*)(bptr1 + k);

        acc[0][0] = __builtin_amdgcn_mfma_f32_16x16x32_bf16(a0, b0, acc[0][0], 0, 0, 0);
        acc[0][1] = __builtin_amdgcn_mfma_f32_16x16x32_bf16(a0, b1, acc[0][1], 0, 0, 0);
        acc[1][0] = __builtin_amdgcn_mfma_f32_16x16x32_bf16(a1, b0, acc[1][0], 0, 0, 0);
        acc[1][1] = __builtin_amdgcn_mfma_f32_16x16x32_bf16(a1, b1, acc[1][1], 0, 0, 0);
    }

#pragma unroll
    for (int bn = 0; bn < 2; ++bn) {
        int col = bcol0 + bn * 16;
        if (col >= N_OUT) continue;
        float bv = bias[col];
#pragma unroll
        for (int am = 0; am < 2; ++am) {
            int rbase = m0 + am * 16 + lhi * 4;
#pragma unroll
            for (int r = 0; r < 4; ++r) {
                float v = acc[am][bn][r] + bv;
                out[(size_t)(rbase + r) * N_OUT + col] = v > 0.0f ? v : 0.0f;
            }
        }
    }
}

// ---------------------------------------------------------------------------
// Kernel 2 (fallback): W stays fp32, converted in-register.
// ---------------------------------------------------------------------------
__global__ __launch_bounds__(256) void mcb_gemm_f32_kernel(
    const __bf16* __restrict__ zbm, const float* __restrict__ W,
    const float* __restrict__ bias, float* __restrict__ out)
{
    const int lane = threadIdx.x & 63;
    const int wave = threadIdx.x >> 6;
    const int wm = wave >> 1;
    const int wn = wave & 1;
    const int llo = lane & 15;
    const int lhi = lane >> 4;

    const int m0 = blockIdx.y * 64 + wm * 32;
    const int n0 = blockIdx.x * 64 + wn * 32;

    f32x4 acc[2][2] = {};

    const int arow0 = m0 + llo;
    const int bcol0 = n0 + llo;
    const int kk = lhi * 8;

    const __bf16* aptr0 = zbm + (size_t)arow0 * D_MCB + kk;
    const __bf16* aptr1 = aptr0 + (size_t)16 * D_MCB;
    const float*  bptr0 = W + (size_t)bcol0 * D_MCB + kk;
    const float*  bptr1 = bptr0 + (size_t)16 * D_MCB;
    const bool bok0 = (bcol0 < N_OUT);
    const bool bok1 = (bcol0 + 16 < N_OUT);

    for (int k = 0; k < D_MCB; k += 32) {
        bf16x8 a0 = *(const bf16x8*)(aptr0 + k);
        bf16x8 a1 = *(const bf16x8*)(aptr1 + k);

        bf16x8 b0 = {}, b1 = {};
        if (bok0) {
            f32x4 w0 = *(const f32x4*)(bptr0 + k);
            f32x4 w1 = *(const f32x4*)(bptr0 + k + 4);
#pragma unroll
            for (int q = 0; q < 4; ++q) { b0[q] = (__bf16)w0[q]; b0[q + 4] = (__bf16)w1[q]; }
        }
        if (bok1) {
            f32x4 w0 = *(const f32x4*)(bptr1 + k);
            f32x4 w1 = *(const f32x4*)(bptr1 + k + 4);
#pragma unroll
            for (int q = 0; q < 4; ++q) { b1[q] = (__bf16)w0[q]; b1[q + 4] = (__bf16)w1[q]; }
        }

        acc[0][0] = __builtin_amdgcn_mfma_f32_16x16x32_bf16(a0, b0, acc[0][0], 0, 0, 0);
        acc[0][1] = __builtin_amdgcn_mfma_f32_16x16x32_bf16(a0, b1, acc[0][1], 0, 0, 0);
        acc[1][0] = __builtin_amdgcn_mfma_f32_16x16x32_bf16(a1, b0, acc[1][0], 0, 0, 0);
        acc[1][1] = __builtin_amdgcn_mfma_f32_16x16x32_bf16(a1, b1, acc[1][1], 0, 0, 0);
    }

#pragma unroll
    for (int bn = 0; bn < 2; ++bn) {
        int col = bcol0 + bn * 16;
        if (col >= N_OUT) continue;
        float bv = bias[col];
#pragma unroll
        for (int am = 0; am < 2; ++am) {
            int rbase = m0 + am * 16 + lhi * 4;
#pragma unroll
            for (int r = 0; r < 4; ++r) {
                float v = acc[am][bn][r] + bv;
                out[(size_t)(rbase + r) * N_OUT + col] = v > 0.0f ? v : 0.0f;
            }
        }
    }
}

extern "C" void kernel_launch(void* const* d_in, const int* in_sizes, int n_in,
                              void* d_out, int out_size, void* d_ws, size_t ws_size,
                              hipStream_t stream) {
    // setup_inputs() order: x0, x1, s1, s2, W, b, h1, h2
    const float* x0   = (const float*)d_in[0];
    const float* x1   = (const float*)d_in[1];
    const float* s1   = (const float*)d_in[2];
    const float* s2   = (const float*)d_in[3];
    const float* W    = (const float*)d_in[4];
    const float* bias = (const float*)d_in[5];
    const int*   h1   = (const int*)d_in[6];
    const int*   h2   = (const int*)d_in[7];
    float* out = (float*)d_out;

    const size_t zb_bytes = (size_t)BATCH * D_MCB * sizeof(__bf16);   // 16,384,000
    const size_t wb_bytes = (size_t)N_OUT * D_MCB * sizeof(__bf16);   // 96,000,000

    __bf16* zbm = (__bf16*)d_ws;

    mcb_pair_kernel<<<BATCH, 256, 0, stream>>>(x0, x1, s1, s2, h1, h2, zbm);

    if (ws_size >= zb_bytes + wb_bytes) {
        __bf16* Wb = (__bf16*)((char*)d_ws + zb_bytes);
        wconv_kernel<<<46875, 256, 0, stream>>>(W, Wb);
        mcb_gemm_bf16_kernel<<<dim3(47, 8), 256, 0, stream>>>(zbm, Wb, bias, out);
    } else {
        mcb_gemm_f32_kernel<<<dim3(47, 8), 256, 0, stream>>>(zbm, W, bias, out);
    }
}

// Round 2
// 1949.336 us; speedup vs baseline: 5.8009x; 5.8009x over previous
//
#include <hip/hip_runtime.h>
#include <stdint.h>

#define BATCH 512
#define D_IN  2048
#define D_MCB 16000
#define N_OUT 3000

typedef __bf16 bf16x8 __attribute__((ext_vector_type(8)));
typedef __bf16 bf16x4 __attribute__((ext_vector_type(4)));
typedef float  f32x4  __attribute__((ext_vector_type(4)));

// Native LDS float atomic add (fire-and-forget). addr = 32-bit LDS byte addr.
__device__ __forceinline__ void lds_fadd(unsigned addr, float v) {
    asm volatile("ds_add_f32 %0, %1" :: "v"(addr), "v"(v) : "memory");
}

// Async global->LDS, 16 bytes per lane. LDS dest must be wave-uniform base
// + lane*16 (it is: offsets are linear in threadIdx).
__device__ __forceinline__ void gload16(const void* g, void* l) {
    __builtin_amdgcn_global_load_lds(
        (const __attribute__((address_space(1))) unsigned*)g,
        (__attribute__((address_space(3))) unsigned*)l,
        16, 0, 0);
}

// ---------------------------------------------------------------------------
// Kernel 1: count-sketch + circular convolution, GATHER with bf16 p2 table.
// (R4 lesson: pair-scatter via ds_add_f32 is DEAD — LDS atomics sustain only
//  ~1 lane-op/3cyc/CU => 10.6ms. Gather's 8x more FMAs still 6.6x faster.)
//   z[b,k] = sum_i a1[b,i] * p2[b, (k + s_i) mod d],  s_i = d - h1[i]
// p2 table in bf16 -> 9 b128/i (2.25 B/FMA), unpack = 1 VALU (<<16, exact).
// LDS = 64 KB p2x(bf16, ~2 periods, XOR-swizzled) + 16 KB idata = 80 KB
// -> 2 blocks/CU. delta = s&7 is wave-uniform -> 8 static FMA wirings.
// ---------------------------------------------------------------------------
__global__ __launch_bounds__(256, 2) void mcb_conv_kernel(
    const float* __restrict__ x0, const float* __restrict__ x1,
    const float* __restrict__ s1, const float* __restrict__ s2,
    const int* __restrict__ h1, const int* __restrict__ h2,
    __bf16* __restrict__ zb)
{
    __shared__ __align__(16) char smem[81920];
    unsigned short* p2x  = (unsigned short*)smem;          // [32768] bf16 bits
    float*          p2f  = (float*)smem;                   // [16000] fp32 overlay
    float2*         idata = (float2*)(smem + 65536);       // [2048] (a1, s bits)

    const int b    = blockIdx.x;
    const int t    = threadIdx.x;
    const int lane = t & 63;
    const int wave = t >> 6;

    // --- phase 1: zero fp32 p2, stage idata ---
    for (int k = t; k < D_MCB; k += 256) p2f[k] = 0.0f;
    for (int i = t; i < D_IN; i += 256) {
        float a1 = s1[i] * x0[b * D_IN + i];
        int   s  = D_MCB - h1[i];                 // in [1, 16000]
        idata[i] = make_float2(a1, __int_as_float(s));
    }
    __syncthreads();

    // --- phase 2: scatter p2 (fp32, plain layout, tiny: 2048 atomics) ---
    for (int j = t; j < D_IN; j += 256) {
        float a2 = s2[j] * x1[b * D_IN + j];
        unsigned addr = (unsigned)(uintptr_t)&p2f[h2[j]];
        lds_fadd(addr, a2);
    }
    __syncthreads();

    // --- phase 3: convert fp32 p2 -> bf16 p2x, replicated to 32768 elems,
    //     XOR-swizzled at 8-elem (16 B) chunks: phys = c ^ ((c>>3)&7).
    //     Register-staged: read all sources, barrier, write (overlay-safe). ---
    bf16x8 stage[16];
#pragma unroll
    for (int m = 0; m < 16; ++m) {
        int c  = t + 256 * m;                     // chunk in [0,4096)
        int e8 = c << 3;                          // elem base, [0,32768)
        if (e8 >= 2 * D_MCB) e8 -= 2 * D_MCB;
        else if (e8 >= D_MCB) e8 -= D_MCB;
        f32x4 lo = *(const f32x4*)(p2f + e8);
        f32x4 hi = *(const f32x4*)(p2f + e8 + 4);
        bf16x8 o;
#pragma unroll
        for (int q = 0; q < 4; ++q) { o[q] = (__bf16)lo[q]; o[q + 4] = (__bf16)hi[q]; }
        stage[m] = o;
    }
    __syncthreads();
#pragma unroll
    for (int m = 0; m < 16; ++m) {
        int c  = t + 256 * m;
        int pc = c ^ ((c >> 3) & 7);
        *(bf16x8*)(p2x + pc * 8) = stage[m];
    }
    __syncthreads();

    // --- phase 4: gather. Lane owns k in [k0, k0+64), wave w covers
    //     [4000w, 4000w+4096) (96-elem overlap masked at store). ---
    const int k0 = wave * 4000 + (lane << 6);     // multiple of 8
    const int K8 = k0 >> 3;

    float zacc[64];
#pragma unroll
    for (int q = 0; q < 64; ++q) zacc[q] = 0.f;

    // w: 9 chunks = 36 dwords; elem e=q+D: dword e>>1, half e&1.
    // bf16->f32: lo half = bits<<16, hi half = bits & 0xffff0000 (both exact).
#define FMAB(D)                                                           \
    {                                                                     \
        const unsigned* wd = (const unsigned*)w;                          \
        _Pragma("unroll")                                                 \
        for (int q = 0; q < 64; ++q) {                                    \
            const int e = q + (D);                                        \
            unsigned dwv  = wd[e >> 1];                                   \
            unsigned bits = (e & 1) ? (dwv & 0xffff0000u) : (dwv << 16);  \
            zacc[q] += a1 * __uint_as_float(bits);                        \
        }                                                                 \
    }

    float2 jd = idata[0];
    for (int i = 0; i < D_IN; ++i) {
        float a1 = jd.x;
        int   s  = __float_as_int(jd.y);
        jd = idata[(i + 1) & (D_IN - 1)];          // broadcast prefetch

        const int c0 = K8 + (s >> 3);              // window chunk base
        const int dl = s & 7;                      // wave-uniform delta

        uint4 w[9];
#pragma unroll
        for (int tt = 0; tt < 9; ++tt) {
            int c = c0 + tt;
            w[tt] = *(const uint4*)(p2x + (c ^ ((c >> 3) & 7)) * 8);
        }

        switch (dl) {
            case 0: FMAB(0) break;
            case 1: FMAB(1) break;
            case 2: FMAB(2) break;
            case 3: FMAB(3) break;
            case 4: FMAB(4) break;
            case 5: FMAB(5) break;
            case 6: FMAB(6) break;
            default: FMAB(7) break;
        }
    }
#undef FMAB

    // --- store bf16 z, masking wave overlap (all bounds % 8 == 0) ---
    const int klim = wave * 4000 + 4000;
#pragma unroll
    for (int g = 0; g < 8; ++g) {
        int kg = k0 + g * 8;
        if (kg < klim) {
            bf16x8 o;
#pragma unroll
            for (int e = 0; e < 8; ++e) o[e] = (__bf16)zacc[g * 8 + e];
            *(bf16x8*)(zb + (size_t)b * D_MCB + kg) = o;
        }
    }
}

// ---------------------------------------------------------------------------
// Kernel 1.5: W fp32 -> bf16 pre-convert (one pass).
// ---------------------------------------------------------------------------
__global__ __launch_bounds__(256) void wconv_kernel(
    const float* __restrict__ W, __bf16* __restrict__ Wb)
{
    size_t i = ((size_t)blockIdx.x * 256 + threadIdx.x) * 4;
    f32x4 w = *(const f32x4*)(W + i);
    bf16x4 o;
#pragma unroll
    for (int q = 0; q < 4; ++q) o[q] = (__bf16)w[q];
    *(bf16x4*)(Wb + i) = o;
}

// ---------------------------------------------------------------------------
// Kernel 2 (R5 rewrite): LDS-staged bf16 GEMM, m97-style.
//   Tile BM=128 x BN=64, BK=64, 4 waves (2M x 2N), double-buffered LDS,
//   global_load_lds width=16, XOR chunk swizzle phys = c ^ (row&7)
//   (2-way residual on ds_read_b128 = free). Grid (47, 4) = 188 blocks.
//   out = relu(z @ Wb^T + bias). A = z [M][K] row-major, B = Wb [N][K].
// ---------------------------------------------------------------------------
__global__ __launch_bounds__(256) void mcb_gemm_tiled_kernel(
    const __bf16* __restrict__ zbm, const __bf16* __restrict__ Wb,
    const float* __restrict__ bias, float* __restrict__ out)
{
    // LDS: A buf 16384 B, B buf 8192 B, x2 buffers = 49152 B
    __shared__ __align__(16) char tile[49152];

    const int t    = threadIdx.x;
    const int lane = t & 63;
    const int wave = t >> 6;
    const int llo  = lane & 15;
    const int lhi  = lane >> 4;
    const int wm   = wave >> 1;            // 0..1 : M strip of 64
    const int wn   = wave & 1;             // 0..1 : N strip of 32

    const int m0 = blockIdx.y * 128;
    const int n0 = blockIdx.x * 64;

    // --- staging source pointers + LDS offsets (linear dest, pre-swizzled src) ---
    const __bf16* asrc[4];
    const __bf16* bsrc[2];
    int aoff[4], boff[2];
#pragma unroll
    for (int p = 0; p < 4; ++p) {
        int f     = (p * 256 + t) * 16;    // byte offset in 16 KB A tile
        int row   = f >> 7;                // 0..127 (128 B per row = 64 bf16)
        int physc = (f >> 4) & 7;
        int logc  = physc ^ (row & 7);     // inverse swizzle on SOURCE
        asrc[p] = zbm + (size_t)(m0 + row) * D_MCB + logc * 8;
        aoff[p] = f;
    }
#pragma unroll
    for (int p = 0; p < 2; ++p) {
        int f     = (p * 256 + t) * 16;    // byte offset in 8 KB B tile
        int row   = f >> 7;                // 0..63
        int wrow  = n0 + row;
        if (wrow > N_OUT - 1) wrow = N_OUT - 1;   // clamp pad rows (masked at store)
        int physc = (f >> 4) & 7;
        int logc  = physc ^ (row & 7);
        bsrc[p] = Wb + (size_t)wrow * D_MCB + logc * 8;
        boff[p] = 16384 + f;
    }

#define STAGE(bufsel, kt)                                                  \
    {                                                                      \
        const int bo_ = (bufsel) * 24576;                                  \
        const int ke_ = (kt) * 64;                                         \
        _Pragma("unroll")                                                  \
        for (int p = 0; p < 4; ++p) gload16(asrc[p] + ke_, tile + bo_ + aoff[p]); \
        _Pragma("unroll")                                                  \
        for (int p = 0; p < 2; ++p) gload16(bsrc[p] + ke_, tile + bo_ + boff[p]); \
    }

    // --- fragment read offsets (swizzled) ---
    int ard[4][2], brd[2][2];
#pragma unroll
    for (int am = 0; am < 4; ++am)
#pragma unroll
        for (int ks = 0; ks < 2; ++ks) {
            int row = wm * 64 + am * 16 + llo;
            int c   = lhi + ks * 4;
            ard[am][ks] = row * 128 + (c ^ (row & 7)) * 16;
        }
#pragma unroll
    for (int bn = 0; bn < 2; ++bn)
#pragma unroll
        for (int ks = 0; ks < 2; ++ks) {
            int row = wn * 32 + bn * 16 + llo;
            int c   = lhi + ks * 4;
            brd[bn][ks] = 16384 + row * 128 + (c ^ (row & 7)) * 16;
        }

    f32x4 acc[4][2] = {};

    STAGE(0, 0);
    __syncthreads();                        // drains vmcnt before first reads

    int buf = 0;
    for (int kt = 0; kt < 250; ++kt) {
        if (kt + 1 < 250) STAGE(buf ^ 1, kt + 1);   // issue next-tile loads first

        const char* base = tile + buf * 24576;
        bf16x8 a[4][2], b[2][2];
#pragma unroll
        for (int am = 0; am < 4; ++am)
#pragma unroll
            for (int ks = 0; ks < 2; ++ks)
                a[am][ks] = *(const bf16x8*)(base + ard[am][ks]);
#pragma unroll
        for (int bn = 0; bn < 2; ++bn)
#pragma unroll
            for (int ks = 0; ks < 2; ++ks)
                b[bn][ks] = *(const bf16x8*)(base + brd[bn][ks]);

#pragma unroll
        for (int ks = 0; ks < 2; ++ks)
#pragma unroll
            for (int am = 0; am < 4; ++am)
#pragma unroll
                for (int bn = 0; bn < 2; ++bn)
                    acc[am][bn] = __builtin_amdgcn_mfma_f32_16x16x32_bf16(
                        a[am][ks], b[bn][ks], acc[am][bn], 0, 0, 0);

        __syncthreads();                    // drains vmcnt+lgkm; next tile ready
        buf ^= 1;
    }
#undef STAGE

    // --- epilogue: C/D layout col=lane&15, row=(lane>>4)*4+r (verified) ---
#pragma unroll
    for (int bn = 0; bn < 2; ++bn) {
        int col = n0 + wn * 32 + bn * 16 + llo;
        if (col < N_OUT) {
            float bv = bias[col];
#pragma unroll
            for (int am = 0; am < 4; ++am) {
                int rbase = m0 + wm * 64 + am * 16 + lhi * 4;
#pragma unroll
                for (int r = 0; r < 4; ++r) {
                    float v = acc[am][bn][r] + bv;
                    out[(size_t)(rbase + r) * N_OUT + col] = v > 0.0f ? v : 0.0f;
                }
            }
        }
    }
}

// ---------------------------------------------------------------------------
// Kernel 2 (fallback): W stays fp32, converted in-register (no workspace).
// ---------------------------------------------------------------------------
__global__ __launch_bounds__(256) void mcb_gemm_f32_kernel(
    const __bf16* __restrict__ zbm, const float* __restrict__ W,
    const float* __restrict__ bias, float* __restrict__ out)
{
    const int lane = threadIdx.x & 63;
    const int wave = threadIdx.x >> 6;
    const int wm = wave >> 1;
    const int wn = wave & 1;
    const int llo = lane & 15;
    const int lhi = lane >> 4;

    const int m0 = blockIdx.y * 64 + wm * 32;
    const int n0 = blockIdx.x * 64 + wn * 32;

    f32x4 acc[2][2] = {};

    const int arow0 = m0 + llo;
    const int bcol0 = n0 + llo;
    const int kk = lhi * 8;

    const __bf16* aptr0 = zbm + (size_t)arow0 * D_MCB + kk;
    const __bf16* aptr1 = aptr0 + (size_t)16 * D_MCB;
    const float*  bptr0 = W + (size_t)bcol0 * D_MCB + kk;
    const float*  bptr1 = bptr0 + (size_t)16 * D_MCB;
    const bool bok0 = (bcol0 < N_OUT);
    const bool bok1 = (bcol0 + 16 < N_OUT);

    for (int k = 0; k < D_MCB; k += 32) {
        bf16x8 a0 = *(const bf16x8*)(aptr0 + k);
        bf16x8 a1 = *(const bf16x8*)(aptr1 + k);

        bf16x8 b0 = {}, b1 = {};
        if (bok0) {
            f32x4 w0 = *(const f32x4*)(bptr0 + k);
            f32x4 w1 = *(const f32x4*)(bptr0 + k + 4);
#pragma unroll
            for (int q = 0; q < 4; ++q) { b0[q] = (__bf16)w0[q]; b0[q + 4] = (__bf16)w1[q]; }
        }
        if (bok1) {
            f32x4 w0 = *(const f32x4*)(bptr1 + k);
            f32x4 w1 = *(const f32x4*)(bptr1 + k + 4);
#pragma unroll
            for (int q = 0; q < 4; ++q) { b1[q] = (__bf16)w0[q]; b1[q + 4] = (__bf16)w1[q]; }
        }

        acc[0][0] = __builtin_amdgcn_mfma_f32_16x16x32_bf16(a0, b0, acc[0][0], 0, 0, 0);
        acc[0][1] = __builtin_amdgcn_mfma_f32_16x16x32_bf16(a0, b1, acc[0][1], 0, 0, 0);
        acc[1][0] = __builtin_amdgcn_mfma_f32_16x16x32_bf16(a1, b0, acc[1][0], 0, 0, 0);
        acc[1][1] = __builtin_amdgcn_mfma_f32_16x16x32_bf16(a1, b1, acc[1][1], 0, 0, 0);
    }

#pragma unroll
    for (int bn = 0; bn < 2; ++bn) {
        int col = bcol0 + bn * 16;
        if (col >= N_OUT) continue;
        float bv = bias[col];
#pragma unroll
        for (int am = 0; am < 2; ++am) {
            int rbase = m0 + am * 16 + lhi * 4;
#pragma unroll
            for (int r = 0; r < 4; ++r) {
                float v = acc[am][bn][r] + bv;
                out[(size_t)(rbase + r) * N_OUT + col] = v > 0.0f ? v : 0.0f;
            }
        }
    }
}

extern "C" void kernel_launch(void* const* d_in, const int* in_sizes, int n_in,
                              void* d_out, int out_size, void* d_ws, size_t ws_size,
                              hipStream_t stream) {
    // setup_inputs() order: x0, x1, s1, s2, W, b, h1, h2
    const float* x0   = (const float*)d_in[0];
    const float* x1   = (const float*)d_in[1];
    const float* s1   = (const float*)d_in[2];
    const float* s2   = (const float*)d_in[3];
    const float* W    = (const float*)d_in[4];
    const float* bias = (const float*)d_in[5];
    const int*   h1   = (const int*)d_in[6];
    const int*   h2   = (const int*)d_in[7];
    float* out = (float*)d_out;

    const size_t zb_bytes = (size_t)BATCH * D_MCB * sizeof(__bf16);   // 16,384,000
    const size_t wb_bytes = (size_t)N_OUT * D_MCB * sizeof(__bf16);   // 96,000,000

    __bf16* zbm = (__bf16*)d_ws;

    mcb_conv_kernel<<<BATCH, 256, 0, stream>>>(x0, x1, s1, s2, h1, h2, zbm);

    if (ws_size >= zb_bytes + wb_bytes) {
        __bf16* Wb = (__bf16*)((char*)d_ws + zb_bytes);
        wconv_kernel<<<46875, 256, 0, stream>>>(W, Wb);
        mcb_gemm_tiled_kernel<<<dim3(47, 4), 256, 0, stream>>>(zbm, Wb, bias, out);
    } else {
        mcb_gemm_f32_kernel<<<dim3(47, 8), 256, 0, stream>>>(zbm, W, bias, out);
    }
}